// Round 3
// baseline (531.234 us; speedup 1.0000x reference)
//
#include <hip/hip_runtime.h>
#include <hip/hip_bf16.h>

// Problem constants (from reference)
#define NXD 432
#define NYD 496
#define NZD 1
#define GD  (NXD * NYD * NZD)   // 214272
#define MAXP 100
#define MAXV 12000
#define SCAN_T 1024
#define CHUNK 210               // ceil(GD / SCAN_T)

// ws layout (int32 elements):
//  [0] flag (1 = inputs are bf16, 0 = f32)
//  [1] nocc (total occupied voxels)
//  [8 .. 8+GD)          counts
//  [8+GD .. 8+2GD)      start   (exclusive prefix of counts)
//  [8+2GD .. 8+3GD)     cursor
//  [8+3GD .. +N)        lin per point
//  [.. +N)              point_idx (bucketed point indices)
//  [.. +MAXV)           occ_list
// total ~4.3 MB

__device__ inline float bf2f(unsigned short u) {
    unsigned int x = ((unsigned int)u) << 16;
    float f;
    __builtin_memcpy(&f, &x, 4);
    return f;
}
__device__ inline unsigned short f2bf(float f) {  // round-to-nearest-even
    unsigned int x;
    __builtin_memcpy(&x, &f, 4);
    unsigned int r = (x + 0x7FFFu + ((x >> 16) & 1u)) >> 16;
    return (unsigned short)r;
}

// Detect whether the input buffer holds f32 or packed bf16.
// Word 4i+2 as f32: if f32 layout it's z in [-3,1] (always in range);
// if bf16 layout its high half is a y-coordinate (|y| up to 39.68, ~8% in range).
__global__ void k_detect(const float* inF, int* ws) {
    __shared__ int s_in;
    if (threadIdx.x == 0) s_in = 0;
    __syncthreads();
    const int samples = 512;
    int cnt = 0;
    for (int i = threadIdx.x; i < samples; i += blockDim.x) {
        float z = inF[4 * i + 2];
        if (z >= -3.01f && z <= 1.01f) cnt++;
    }
    atomicAdd(&s_in, cnt);
    __syncthreads();
    if (threadIdx.x == 0) ws[0] = (2 * s_in < samples) ? 1 : 0;
}

__global__ void k_lin(const void* in, int* ws, int N) {
    int i = blockIdx.x * blockDim.x + threadIdx.x;
    if (i >= N) return;
    int flag = ws[0];
    float x, y, z;
    if (flag) {
        const unsigned short* p = (const unsigned short*)in;
        x = bf2f(p[4 * i + 0]);
        y = bf2f(p[4 * i + 1]);
        z = bf2f(p[4 * i + 2]);
    } else {
        const float* p = (const float*)in;
        x = p[4 * i + 0];
        y = p[4 * i + 1];
        z = p[4 * i + 2];
    }
    // match jnp: floor((p - rmin) / vsize), f32 IEEE division (no fast-math)
    int vx = (int)floorf((x - 0.0f)    / 0.16f);
    int vy = (int)floorf((y + 39.68f)  / 0.16f);
    int vz = (int)floorf((z + 3.0f)    / 4.0f);
    int l;
    if (vx >= 0 && vx < NXD && vy >= 0 && vy < NYD && vz >= 0 && vz < NZD)
        l = vz * GD + vy * NXD + vx;
    else
        l = GD;
    int* counts = ws + 8;
    int* lin    = ws + 8 + 3 * GD;
    lin[i] = l;
    if (l < GD) atomicAdd(&counts[l], 1);
}

// Single-block scan of (counts, occ_flag) pairs over GD voxels.
// Produces start[], zeroed cursor[], occ_list[], nocc.
__global__ void __launch_bounds__(SCAN_T) k_scan(int* ws, int N) {
    __shared__ int sc[SCAN_T];
    __shared__ int so[SCAN_T];
    int* counts = ws + 8;
    int* start  = counts + GD;
    int* cursor = start + GD;
    int* occ    = ws + 8 + 3 * GD + 2 * N;
    int t = threadIdx.x;
    int lo = t * CHUNK;
    int hi = min(GD, lo + CHUNK);
    int sumc = 0, sumo = 0;
    for (int v = lo; v < hi; v++) {
        int c = counts[v];
        sumc += c;
        sumo += (c > 0);
    }
    sc[t] = sumc;
    so[t] = sumo;
    __syncthreads();
    for (int off = 1; off < SCAN_T; off <<= 1) {
        int a = (t >= off) ? sc[t - off] : 0;
        int b = (t >= off) ? so[t - off] : 0;
        __syncthreads();
        sc[t] += a;
        so[t] += b;
        __syncthreads();
    }
    if (t == SCAN_T - 1) ws[1] = so[t];  // total occupied
    int rc = sc[t] - sumc;  // exclusive offsets for this chunk
    int ro = so[t] - sumo;
    for (int v = lo; v < hi; v++) {
        int c = counts[v];
        start[v]  = rc;
        cursor[v] = 0;
        if (c > 0) {
            if (ro < MAXV) occ[ro] = v;
            ro++;
        }
        rc += c;
    }
}

__global__ void k_place(int* ws, int N) {
    int i = blockIdx.x * blockDim.x + threadIdx.x;
    if (i >= N) return;
    int* counts = ws + 8;
    int* start  = counts + GD;
    int* cursor = start + GD;
    int* lin    = ws + 8 + 3 * GD;
    int* pidx   = lin + N;
    int l = lin[i];
    if (l < GD) {
        int pos = start[l] + atomicAdd(&cursor[l], 1);
        pidx[pos] = i;
    }
}

// One block per output voxel slot. Sorts the voxel's point indices ascending
// (reproducing stable-argsort slot order), writes all MAXP*4 values (zeros
// beyond count) + coords + num_points. Covers every output element each call.
__global__ void k_out(const void* in, const int* ws, void* out, int N) {
    __shared__ int idxs[MAXP];
    __shared__ int sv, scnt, sst;
    int s = blockIdx.x;
    int t = threadIdx.x;
    int flag = ws[0];
    int nocc = ws[1];
    const int* counts = ws + 8;
    const int* start  = counts + GD;
    const int* lin    = ws + 8 + 3 * GD;
    const int* pidx   = lin + N;
    const int* occ    = pidx + N;

    bool pad = (s >= nocc);
    int v = 0, cnt = 0, c = 0;
    if (!pad) {  // block-uniform branch: barriers are safe
        if (t == 0) {
            sv = occ[s];
            scnt = counts[sv];
            sst = start[sv];
        }
        __syncthreads();
        v = sv;
        cnt = scnt;
        c = min(cnt, MAXP);
        for (int k = t; k < c; k += blockDim.x) idxs[k] = pidx[sst + k];
        __syncthreads();
        if (t == 0) {  // insertion sort (c is ~<=10 for this input)
            for (int a = 1; a < c; a++) {
                int key = idxs[a];
                int b = a - 1;
                while (b >= 0 && idxs[b] > key) { idxs[b + 1] = idxs[b]; b--; }
                idxs[b + 1] = key;
            }
        }
        __syncthreads();
    }

    const size_t VOXN = (size_t)MAXV * MAXP * 4;   // 4,800,000
    const size_t CO   = VOXN;                      // coords base
    const size_t NU   = VOXN + (size_t)MAXV * 3;   // num_points base

    int zc = 0, yc = 0, xc = 0;
    if (!pad) {
        zc = v / GD;          // 0 (NZ=1)
        int rem = v % GD;
        yc = rem / NXD;
        xc = rem % NXD;
    }

    if (flag) {
        unsigned short* o = (unsigned short*)out;
        const unsigned short* p = (const unsigned short*)in;
        size_t base = (size_t)s * (MAXP * 4);
        for (int e = t; e < MAXP * 4; e += blockDim.x) {
            int k = e >> 2, j = e & 3;
            unsigned short val = 0;
            if (!pad && k < c) val = p[(size_t)idxs[k] * 4 + j];  // exact copy
            o[base + e] = val;
        }
        if (t < 4) {
            int val;
            size_t off;
            if (t < 3) {
                val = pad ? -1 : (t == 0 ? zc : (t == 1 ? yc : xc));
                off = CO + (size_t)s * 3 + t;
            } else {
                val = pad ? 0 : cnt;
                off = NU + s;
            }
            o[off] = f2bf((float)val);
        }
    } else {
        float* o = (float*)out;
        const float* p = (const float*)in;
        size_t base = (size_t)s * (MAXP * 4);
        for (int e = t; e < MAXP * 4; e += blockDim.x) {
            int k = e >> 2, j = e & 3;
            float val = 0.0f;
            if (!pad && k < c) val = p[(size_t)idxs[k] * 4 + j];  // exact copy
            o[base + e] = val;
        }
        if (t < 4) {
            int val;
            size_t off;
            if (t < 3) {
                val = pad ? -1 : (t == 0 ? zc : (t == 1 ? yc : xc));
                off = CO + (size_t)s * 3 + t;
            } else {
                val = pad ? 0 : cnt;
                off = NU + s;
            }
            o[off] = (float)val;
        }
    }
}

extern "C" void kernel_launch(void* const* d_in, const int* in_sizes, int n_in,
                              void* d_out, int out_size, void* d_ws, size_t ws_size,
                              hipStream_t stream) {
    const void* in = d_in[0];
    int N = in_sizes[0] / 4;   // 200000 points x 4 components
    int* ws = (int*)d_ws;

    // zero the per-voxel counts (cursor is zeroed inside k_scan)
    hipMemsetAsync(ws + 8, 0, (size_t)GD * sizeof(int), stream);

    k_detect<<<1, 256, 0, stream>>>((const float*)in, ws);
    k_lin<<<(N + 255) / 256, 256, 0, stream>>>(in, ws, N);
    k_scan<<<1, SCAN_T, 0, stream>>>(ws, N);
    k_place<<<(N + 255) / 256, 256, 0, stream>>>(ws, N);
    k_out<<<MAXV, 128, 0, stream>>>(in, ws, d_out, N);
}

// Round 4
// 58.528 us; speedup vs baseline: 9.0766x; 9.0766x over previous
//
#include <hip/hip_runtime.h>
#include <hip/hip_bf16.h>

// Problem constants (from reference)
#define NXD 432
#define NYD 496
#define NZD 1
#define GD  (NXD * NYD * NZD)   // 214272
#define MAXP 100
#define MAXV 12000

// hierarchical scan config
#define SCB   256               // threads per scan block
#define ITEMS 1024              // elements per scan block (4 tiles of 256)
#define NB    210               // ceil(GD / ITEMS)

// ws layout (int32 elements):
//  [0] flag (1 = inputs are bf16, 0 = f32)
//  [1] nocc (total occupied voxels)
//  [8 .. 8+GD)              counts
//  [8+GD .. 8+2GD)          start   (exclusive prefix of counts)
//  [8+2GD .. 8+3GD)         cursor
//  [8+3GD .. +N)            lin per point
//  [.. +N)                  point_idx (bucketed point indices)
//  [.. +MAXV)               occ_list
//  [.. +NB)                 pc (block partial sums of counts -> exclusive)
//  [.. +NB)                 po (block partial sums of occ flags -> exclusive)
// total ~4.2 MB

__device__ inline float bf2f(unsigned short u) {
    unsigned int x = ((unsigned int)u) << 16;
    float f;
    __builtin_memcpy(&f, &x, 4);
    return f;
}
__device__ inline unsigned short f2bf(float f) {  // round-to-nearest-even
    unsigned int x;
    __builtin_memcpy(&x, &f, 4);
    unsigned int r = (x + 0x7FFFu + ((x >> 16) & 1u)) >> 16;
    return (unsigned short)r;
}

// Detect whether the input buffer holds f32 or packed bf16.
// Word 4i+2 as f32: if f32 layout it's z in [-3,1] (always in range);
// if bf16 layout its high half is a y-coordinate (|y| up to 39.68, ~8% in range).
__global__ void k_detect(const float* inF, int* ws) {
    __shared__ int s_in;
    if (threadIdx.x == 0) s_in = 0;
    __syncthreads();
    const int samples = 512;
    int cnt = 0;
    for (int i = threadIdx.x; i < samples; i += blockDim.x) {
        float z = inF[4 * i + 2];
        if (z >= -3.01f && z <= 1.01f) cnt++;
    }
    atomicAdd(&s_in, cnt);
    __syncthreads();
    if (threadIdx.x == 0) ws[0] = (2 * s_in < samples) ? 1 : 0;
}

__global__ void k_lin(const void* in, int* ws, int N) {
    int i = blockIdx.x * blockDim.x + threadIdx.x;
    if (i >= N) return;
    int flag = ws[0];
    float x, y, z;
    if (flag) {
        const unsigned short* p = (const unsigned short*)in;
        x = bf2f(p[4 * i + 0]);
        y = bf2f(p[4 * i + 1]);
        z = bf2f(p[4 * i + 2]);
    } else {
        const float* p = (const float*)in;
        x = p[4 * i + 0];
        y = p[4 * i + 1];
        z = p[4 * i + 2];
    }
    // match jnp: floor((p - rmin) / vsize), f32 IEEE division (no fast-math)
    int vx = (int)floorf((x - 0.0f)    / 0.16f);
    int vy = (int)floorf((y + 39.68f)  / 0.16f);
    int vz = (int)floorf((z + 3.0f)    / 4.0f);
    int l;
    if (vx >= 0 && vx < NXD && vy >= 0 && vy < NYD && vz >= 0 && vz < NZD)
        l = vz * GD + vy * NXD + vx;
    else
        l = GD;
    int* counts = ws + 8;
    int* lin    = ws + 8 + 3 * GD;
    lin[i] = l;
    if (l < GD) atomicAdd(&counts[l], 1);
}

// --- hierarchical scan over GD voxels: (counts, occ_flag) pairs ---

// Phase 1: per-block partial sums (coalesced tiles of 256)
__global__ void __launch_bounds__(SCB) k_partial(int* ws, int N) {
    const int* counts = ws + 8;
    int* pc = ws + 8 + 3 * GD + 2 * N + MAXV;
    int* po = pc + NB;
    __shared__ int sc[SCB], so[SCB];
    int b = blockIdx.x, t = threadIdx.x;
    int base = b * ITEMS;
    int sumc = 0, sumo = 0;
    for (int k = 0; k < ITEMS; k += SCB) {
        int i = base + k + t;
        if (i < GD) {
            int c = counts[i];
            sumc += c;
            sumo += (c > 0);
        }
    }
    sc[t] = sumc;
    so[t] = sumo;
    __syncthreads();
    for (int off = SCB / 2; off > 0; off >>= 1) {
        if (t < off) { sc[t] += sc[t + off]; so[t] += so[t + off]; }
        __syncthreads();
    }
    if (t == 0) { pc[b] = sc[0]; po[b] = so[0]; }
}

// Phase 2: one small block scans the NB partials (exclusive), writes nocc
__global__ void __launch_bounds__(256) k_scanp(int* ws, int N) {
    int* pc = ws + 8 + 3 * GD + 2 * N + MAXV;
    int* po = pc + NB;
    __shared__ int sc[256], so[256];
    int t = threadIdx.x;
    int c = (t < NB) ? pc[t] : 0;
    int o = (t < NB) ? po[t] : 0;
    sc[t] = c;
    so[t] = o;
    __syncthreads();
    for (int off = 1; off < 256; off <<= 1) {
        int a  = (t >= off) ? sc[t - off] : 0;
        int b2 = (t >= off) ? so[t - off] : 0;
        __syncthreads();
        sc[t] += a;
        so[t] += b2;
        __syncthreads();
    }
    if (t < NB) { pc[t] = sc[t] - c; po[t] = so[t] - o; }  // exclusive
    if (t == 255) ws[1] = so[255];                          // total occupied
}

// Phase 3: per-block tile scans + apply: start/cursor/occ
__global__ void __launch_bounds__(SCB) k_apply(int* ws, int N) {
    const int* counts = ws + 8;
    int* start  = ws + 8 + GD;
    int* cursor = start + GD;
    int* occ    = ws + 8 + 3 * GD + 2 * N;
    const int* pc = occ + MAXV;
    const int* po = pc + NB;
    __shared__ int sc[SCB], so[SCB];
    int b = blockIdx.x, t = threadIdx.x;
    int rc = pc[b];
    int ro = po[b];
    int base = b * ITEMS;
    for (int k = 0; k < ITEMS; k += SCB) {
        int i = base + k + t;
        int c = (i < GD) ? counts[i] : 0;
        int f = (c > 0) ? 1 : 0;
        sc[t] = c;
        so[t] = f;
        __syncthreads();
        for (int off = 1; off < SCB; off <<= 1) {
            int a  = (t >= off) ? sc[t - off] : 0;
            int b2 = (t >= off) ? so[t - off] : 0;
            __syncthreads();
            sc[t] += a;
            so[t] += b2;
            __syncthreads();
        }
        if (i < GD) {
            int exc = sc[t] - c;   // exclusive within tile
            int exo = so[t] - f;
            start[i]  = rc + exc;
            cursor[i] = 0;
            if (f) {
                int r = ro + exo;
                if (r < MAXV) occ[r] = i;
            }
        }
        rc += sc[SCB - 1];  // tile totals (inclusive of last lane)
        ro += so[SCB - 1];
        __syncthreads();    // protect sc/so before next tile overwrites
    }
}

__global__ void k_place(int* ws, int N) {
    int i = blockIdx.x * blockDim.x + threadIdx.x;
    if (i >= N) return;
    int* counts = ws + 8;
    int* start  = counts + GD;
    int* cursor = start + GD;
    int* lin    = ws + 8 + 3 * GD;
    int* pidx   = lin + N;
    int l = lin[i];
    if (l < GD) {
        int pos = start[l] + atomicAdd(&cursor[l], 1);
        pidx[pos] = i;
    }
}

// One block per output voxel slot. Sorts the voxel's point indices ascending
// (reproducing stable-argsort slot order), writes all MAXP*4 values (zeros
// beyond count) + coords + num_points. Covers every output element each call.
__global__ void k_out(const void* in, const int* ws, void* out, int N) {
    __shared__ int idxs[MAXP];
    __shared__ int sv, scnt, sst;
    int s = blockIdx.x;
    int t = threadIdx.x;
    int flag = ws[0];
    int nocc = ws[1];
    const int* counts = ws + 8;
    const int* start  = counts + GD;
    const int* lin    = ws + 8 + 3 * GD;
    const int* pidx   = lin + N;
    const int* occ    = pidx + N;

    bool pad = (s >= nocc);
    int v = 0, cnt = 0, c = 0;
    if (!pad) {  // block-uniform branch: barriers are safe
        if (t == 0) {
            sv = occ[s];
            scnt = counts[sv];
            sst = start[sv];
        }
        __syncthreads();
        v = sv;
        cnt = scnt;
        c = min(cnt, MAXP);
        for (int k = t; k < c; k += blockDim.x) idxs[k] = pidx[sst + k];
        __syncthreads();
        if (t == 0) {  // insertion sort (c is ~<=10 for this input)
            for (int a = 1; a < c; a++) {
                int key = idxs[a];
                int b = a - 1;
                while (b >= 0 && idxs[b] > key) { idxs[b + 1] = idxs[b]; b--; }
                idxs[b + 1] = key;
            }
        }
        __syncthreads();
    }

    const size_t VOXN = (size_t)MAXV * MAXP * 4;   // 4,800,000
    const size_t CO   = VOXN;                      // coords base
    const size_t NU   = VOXN + (size_t)MAXV * 3;   // num_points base

    int zc = 0, yc = 0, xc = 0;
    if (!pad) {
        zc = v / GD;          // 0 (NZ=1)
        int rem = v % GD;
        yc = rem / NXD;
        xc = rem % NXD;
    }

    if (flag) {
        unsigned short* o = (unsigned short*)out;
        const unsigned short* p = (const unsigned short*)in;
        size_t base = (size_t)s * (MAXP * 4);
        for (int e = t; e < MAXP * 4; e += blockDim.x) {
            int k = e >> 2, j = e & 3;
            unsigned short val = 0;
            if (!pad && k < c) val = p[(size_t)idxs[k] * 4 + j];  // exact copy
            o[base + e] = val;
        }
        if (t < 4) {
            int val;
            size_t off;
            if (t < 3) {
                val = pad ? -1 : (t == 0 ? zc : (t == 1 ? yc : xc));
                off = CO + (size_t)s * 3 + t;
            } else {
                val = pad ? 0 : cnt;
                off = NU + s;
            }
            o[off] = f2bf((float)val);
        }
    } else {
        float* o = (float*)out;
        const float* p = (const float*)in;
        size_t base = (size_t)s * (MAXP * 4);
        for (int e = t; e < MAXP * 4; e += blockDim.x) {
            int k = e >> 2, j = e & 3;
            float val = 0.0f;
            if (!pad && k < c) val = p[(size_t)idxs[k] * 4 + j];  // exact copy
            o[base + e] = val;
        }
        if (t < 4) {
            int val;
            size_t off;
            if (t < 3) {
                val = pad ? -1 : (t == 0 ? zc : (t == 1 ? yc : xc));
                off = CO + (size_t)s * 3 + t;
            } else {
                val = pad ? 0 : cnt;
                off = NU + s;
            }
            o[off] = (float)val;
        }
    }
}

extern "C" void kernel_launch(void* const* d_in, const int* in_sizes, int n_in,
                              void* d_out, int out_size, void* d_ws, size_t ws_size,
                              hipStream_t stream) {
    const void* in = d_in[0];
    int N = in_sizes[0] / 4;   // 200000 points x 4 components
    int* ws = (int*)d_ws;

    // zero the per-voxel counts (cursor is zeroed inside k_apply)
    hipMemsetAsync(ws + 8, 0, (size_t)GD * sizeof(int), stream);

    k_detect<<<1, 256, 0, stream>>>((const float*)in, ws);
    k_lin<<<(N + 255) / 256, 256, 0, stream>>>(in, ws, N);
    k_partial<<<NB, SCB, 0, stream>>>(ws, N);
    k_scanp<<<1, 256, 0, stream>>>(ws, N);
    k_apply<<<NB, SCB, 0, stream>>>(ws, N);
    k_place<<<(N + 255) / 256, 256, 0, stream>>>(ws, N);
    k_out<<<MAXV, 128, 0, stream>>>(in, ws, d_out, N);
}